// Round 6
// baseline (126.452 us; speedup 1.0000x reference)
//
#include <hip/hip_runtime.h>
#include <hip/hip_cooperative_groups.h>
#include <math.h>

namespace cg = cooperative_groups;

// Problem constants (fixed by setup_inputs): B=128, E=512, L=128, D=128, K=5
#define B_ 128
#define E_ 512
#define L_ 128
#define D_ 128
#define K_ 5
#define N_ (B_ * E_)                 // 65536 rows
#define ROWOUT (B_ * K_)             // 640 output rows
#define OUT_TENSOR_SZ (ROWOUT * L_)  // 81920

#define GBLK 1024
#define GTHR 256

// Single fused cooperative kernel:
//  phase 1: cosine for all rows (EXACT R1 per-row math: 32 lanes x float4,
//           sequential dot in chunk, xor-tree 16..1 across the 32-lane half)
//  grid sync
//  phase 2: blocks 0..127 do softmax + top-5 + gather, reproducing the
//           512-thread reduction tree bit-exactly with 256 threads.
__global__ __launch_bounds__(GTHR, 4) void fused_retriever_kernel(
        const float* __restrict__ a,   const float* __restrict__ b,
        const int* __restrict__ ids_c, const int* __restrict__ ids_e,
        const int* __restrict__ m_c,   const int* __restrict__ m_e,
        const int* __restrict__ t_c,   const int* __restrict__ t_e,
        float* __restrict__ cosout,    float* __restrict__ out) {
    // ---------------- phase 1: cosine, 16 rows per wave ----------------
    const int wave_g = (blockIdx.x * GTHR + threadIdx.x) >> 6;   // 0..4095
    const int lane   = threadIdx.x & 63;
    const int half   = lane >> 5;
    const int l32    = lane & 31;

    #pragma unroll
    for (int grp = 0; grp < 4; ++grp) {
        const int base = wave_g * 16 + grp * 4;
        float4 av[2], bv[2];
        #pragma unroll
        for (int it = 0; it < 2; ++it) {
            const size_t row = (size_t)(base + it * 2 + half);
            av[it] = reinterpret_cast<const float4*>(a)[row * (D_ / 4) + l32];
            bv[it] = reinterpret_cast<const float4*>(b)[row * (D_ / 4) + l32];
        }
        #pragma unroll
        for (int it = 0; it < 2; ++it) {
            float4 A = av[it], Bv = bv[it];
            float dot = A.x * Bv.x + A.y * Bv.y + A.z * Bv.z + A.w * Bv.w;
            float na  = A.x * A.x + A.y * A.y + A.z * A.z + A.w * A.w;
            float nb  = Bv.x * Bv.x + Bv.y * Bv.y + Bv.z * Bv.z + Bv.w * Bv.w;
            #pragma unroll
            for (int o = 16; o; o >>= 1) {       // within each 32-lane half
                dot += __shfl_xor(dot, o);
                na  += __shfl_xor(na,  o);
                nb  += __shfl_xor(nb,  o);
            }
            if (l32 == 0) {
                const float eps = 1e-8f;
                float denom = fmaxf(sqrtf(na), eps) * fmaxf(sqrtf(nb), eps);
                cosout[base + it * 2 + half] = dot / denom;
            }
        }
    }

    cg::this_grid().sync();

    // ---------------- phase 2: blocks 0..127, one batch each ----------------
    if (blockIdx.x >= B_) return;
    const int bb  = blockIdx.x;
    const int t   = threadIdx.x;        // 0..255
    const int wid = t >> 6;             // 0..3

    __shared__ float red[8];
    __shared__ float ps[E_];
    __shared__ int   topidx[K_];

    // thread t holds e = t (virtual wave wid) and e = t+256 (virtual wave wid+4)
    float v0 = cosout[bb * E_ + t];
    float v1 = cosout[bb * E_ + 256 + t];

    // block max (fmax is exact -> any reduction shape gives identical bits)
    float m = fmaxf(v0, v1);
    #pragma unroll
    for (int o = 32; o; o >>= 1) m = fmaxf(m, __shfl_xor(m, o));
    if (lane == 0) red[wid] = m;
    __syncthreads();
    float mall = red[0];
    #pragma unroll
    for (int i = 1; i < 4; i++) mall = fmaxf(mall, red[i]);
    __syncthreads();

    // sum of exp: two 64-lane xor-trees per wave -> red[0..7], identical
    // tree + sequential order as the 512-thread version.
    float ex0 = expf(v0 - mall);
    float ex1 = expf(v1 - mall);
    float s0 = ex0, s1 = ex1;
    #pragma unroll
    for (int o = 32; o; o >>= 1) { s0 += __shfl_xor(s0, o); s1 += __shfl_xor(s1, o); }
    if (lane == 0) { red[wid] = s0; red[wid + 4] = s1; }
    __syncthreads();
    float sall = 0.f;
    #pragma unroll
    for (int i = 0; i < 8; i++) sall += red[i];

    ps[t]       = ex0 / sall;
    ps[t + 256] = ex1 / sall;
    __syncthreads();

    // ---- top-5 entirely within wave 0, registers only (identical to R1) ----
    if (wid == 0) {
        float vals[8];
        #pragma unroll
        for (int j = 0; j < 8; j++) vals[j] = ps[j * 64 + lane];

        for (int k = 0; k < K_; k++) {
            float val = vals[0];
            int   idx = lane;
            #pragma unroll
            for (int j = 1; j < 8; j++) {
                if (vals[j] > val) { val = vals[j]; idx = j * 64 + lane; }
            }
            #pragma unroll
            for (int o = 32; o; o >>= 1) {
                float ov = __shfl_xor(val, o);
                int   oi = __shfl_xor(idx, o);
                if (ov > val || (ov == val && oi < idx)) { val = ov; idx = oi; }
            }
            if (lane == 0) {
                out[bb * K_ + k] = val;
                topidx[k] = idx;
            }
            #pragma unroll
            for (int j = 0; j < 8; j++) {
                if ((idx >> 6) == j && (idx & 63) == lane) vals[j] = -INFINITY;
            }
        }
    }
    __syncthreads();

    // ---- gather: wave w handles rows k = w, w+4 (k < 5) ----
    for (int k = wid; k < K_; k += 4) {
        const int r = bb * K_ + k;
        const size_t crow = (size_t)(bb * E_ + k) * L_;
        const size_t erow = (size_t)(bb * E_ + topidx[k]) * L_;
        const int q  = lane & 31;       // int4 index within a row (0..31)
        const int hi = lane >> 5;       // 0 -> claim-side, 1 -> evidence-side
        const int4* s0p = reinterpret_cast<const int4*>(hi ? (ids_e + erow) : (ids_c + crow));
        const int4* s1p = reinterpret_cast<const int4*>(hi ? (m_e   + erow) : (m_c   + crow));
        const int4* s2p = reinterpret_cast<const int4*>(hi ? (t_e   + erow) : (t_c   + crow));
        float4* d0 = reinterpret_cast<float4*>(out + 640 + (size_t)(0 + hi) * OUT_TENSOR_SZ + (size_t)r * L_);
        float4* d1 = reinterpret_cast<float4*>(out + 640 + (size_t)(2 + hi) * OUT_TENSOR_SZ + (size_t)r * L_);
        float4* d2 = reinterpret_cast<float4*>(out + 640 + (size_t)(4 + hi) * OUT_TENSOR_SZ + (size_t)r * L_);
        int4 w0 = s0p[q];
        int4 w1 = s1p[q];
        int4 w2 = s2p[q];
        d0[q] = make_float4((float)w0.x, (float)w0.y, (float)w0.z, (float)w0.w);
        d1[q] = make_float4((float)w1.x, (float)w1.y, (float)w1.z, (float)w1.w);
        d2[q] = make_float4((float)w2.x, (float)w2.y, (float)w2.z, (float)w2.w);
    }
}

extern "C" void kernel_launch(void* const* d_in, const int* in_sizes, int n_in,
                              void* d_out, int out_size, void* d_ws, size_t ws_size,
                              hipStream_t stream) {
    const float* claim_vec    = (const float*)d_in[0];
    const float* evidence_vec = (const float*)d_in[1];
    const int*   ids_claim    = (const int*)d_in[2];
    const int*   ids_evidence = (const int*)d_in[3];
    const int*   masks_claim  = (const int*)d_in[4];
    const int*   masks_evid   = (const int*)d_in[5];
    const int*   token_claim  = (const int*)d_in[6];
    const int*   token_evid   = (const int*)d_in[7];

    float* cos_ws = (float*)d_ws;   // N_ floats
    float* out    = (float*)d_out;

    void* args[] = {
        (void*)&claim_vec, (void*)&evidence_vec,
        (void*)&ids_claim, (void*)&ids_evidence,
        (void*)&masks_claim, (void*)&masks_evid,
        (void*)&token_claim, (void*)&token_evid,
        (void*)&cos_ws, (void*)&out,
    };
    hipLaunchCooperativeKernel((const void*)fused_retriever_kernel,
                               dim3(GBLK), dim3(GTHR), args, 0, stream);
}

// Round 7
// 23.966 us; speedup vs baseline: 5.2763x; 5.2763x over previous
//
#include <hip/hip_runtime.h>
#include <math.h>

// Problem constants (fixed by setup_inputs): B=128, E=512, L=128, D=128, K=5
#define B_ 128
#define E_ 512
#define L_ 128
#define D_ 128
#define K_ 5
#define N_ (B_ * E_)                 // 65536 rows
#define ROWOUT (B_ * K_)             // 640 output rows
#define OUT_TENSOR_SZ (ROWOUT * L_)  // 81920

// ONE kernel, one block per batch (128 blocks x 1024 threads).
// Phase 1: cosine for this batch's 512 rows -> LDS. EXACT R1 per-row math:
//          each 32-lane half-wave owns one row; per-lane float4 partial,
//          xor-tree (16,8,4,2,1). Software prefetch (next iter's loads issued
//          before current reduction).
// Phase 2: threads 0..511 run the bit-identical R1 softmax + top-5.
// Phase 3: waves 0..4 gather (identical to R1).
// No workspace, no second launch, no grid sync.
__global__ __launch_bounds__(1024) void fused_retriever_kernel(
        const float* __restrict__ a,   const float* __restrict__ bvec,
        const int* __restrict__ ids_c, const int* __restrict__ ids_e,
        const int* __restrict__ m_c,   const int* __restrict__ m_e,
        const int* __restrict__ t_c,   const int* __restrict__ t_e,
        float* __restrict__ out) {
    const int b    = blockIdx.x;        // batch
    const int t    = threadIdx.x;       // 0..1023
    const int h    = t >> 5;            // half-wave id 0..31
    const int l32  = t & 31;
    const int lane = t & 63;
    const int wid  = t >> 6;            // 0..15

    __shared__ float cosv[E_];
    __shared__ float ps[E_];
    __shared__ float red[8];
    __shared__ int   topidx[K_];

    // ---------------- phase 1: cosine for rows b*512 .. b*512+511 ----------
    const size_t rowbase = (size_t)b * E_;
    const float4* ap = reinterpret_cast<const float4*>(a)    + (rowbase + h) * (D_ / 4) + l32;
    const float4* bp = reinterpret_cast<const float4*>(bvec) + (rowbase + h) * (D_ / 4) + l32;
    const int rstride = 32 * (D_ / 4);  // float4 stride per iteration (32 rows)

    float4 A0 = ap[0];
    float4 B0 = bp[0];
    #pragma unroll
    for (int it = 0; it < 16; ++it) {
        float4 A1, B1;
        if (it < 15) { A1 = ap[(it + 1) * rstride]; B1 = bp[(it + 1) * rstride]; }
        float dot = A0.x * B0.x + A0.y * B0.y + A0.z * B0.z + A0.w * B0.w;
        float na  = A0.x * A0.x + A0.y * A0.y + A0.z * A0.z + A0.w * A0.w;
        float nb  = B0.x * B0.x + B0.y * B0.y + B0.z * B0.z + B0.w * B0.w;
        #pragma unroll
        for (int o = 16; o; o >>= 1) {      // stays within the 32-lane half
            dot += __shfl_xor(dot, o);
            na  += __shfl_xor(na,  o);
            nb  += __shfl_xor(nb,  o);
        }
        if (l32 == 0) {
            const float eps = 1e-8f;
            float denom = fmaxf(sqrtf(na), eps) * fmaxf(sqrtf(nb), eps);
            cosv[it * 32 + h] = dot / denom;
        }
        A0 = A1; B0 = B1;
    }
    __syncthreads();

    // ---------------- phase 2: softmax (threads 0..511, bit-identical to R1) ----
    float v = 0.f, ex = 0.f;
    if (t < 512) {
        v = cosv[t];
        float m = v;
        #pragma unroll
        for (int o = 32; o; o >>= 1) m = fmaxf(m, __shfl_xor(m, o));
        if (lane == 0) red[wid] = m;
    }
    __syncthreads();
    float mall = 0.f;
    if (t < 512) {
        mall = red[0];
        #pragma unroll
        for (int i = 1; i < 8; i++) mall = fmaxf(mall, red[i]);
    }
    __syncthreads();
    if (t < 512) {
        ex = expf(v - mall);
        float s = ex;
        #pragma unroll
        for (int o = 32; o; o >>= 1) s += __shfl_xor(s, o);
        if (lane == 0) red[wid] = s;
    }
    __syncthreads();
    if (t < 512) {
        float sall = 0.f;
        #pragma unroll
        for (int i = 0; i < 8; i++) sall += red[i];
        ps[t] = ex / sall;
    }
    __syncthreads();

    // ---- top-5 entirely within wave 0, registers only (identical to R1) ----
    if (wid == 0) {
        float vals[8];
        #pragma unroll
        for (int j = 0; j < 8; j++) vals[j] = ps[j * 64 + lane];

        for (int k = 0; k < K_; k++) {
            float val = vals[0];
            int   idx = lane;
            #pragma unroll
            for (int j = 1; j < 8; j++) {
                if (vals[j] > val) { val = vals[j]; idx = j * 64 + lane; }
            }
            #pragma unroll
            for (int o = 32; o; o >>= 1) {
                float ov = __shfl_xor(val, o);
                int   oi = __shfl_xor(idx, o);
                if (ov > val || (ov == val && oi < idx)) { val = ov; idx = oi; }
            }
            if (lane == 0) {
                out[b * K_ + k] = val;
                topidx[k] = idx;
            }
            #pragma unroll
            for (int j = 0; j < 8; j++) {
                if ((idx >> 6) == j && (idx & 63) == lane) vals[j] = -INFINITY;
            }
        }
    }
    __syncthreads();

    // ---- phase 3: gather, waves 0..4 (identical to R1) ----
    if (wid < K_) {
        const int k = wid;
        const int r = b * K_ + k;
        const size_t crow = (size_t)(b * E_ + k) * L_;
        const size_t erow = (size_t)(b * E_ + topidx[k]) * L_;
        const int q  = lane & 31;       // int4 index within a row (0..31)
        const int hi = lane >> 5;       // 0 -> claim-side, 1 -> evidence-side
        const int4* s0 = reinterpret_cast<const int4*>(hi ? (ids_e + erow) : (ids_c + crow));
        const int4* s1 = reinterpret_cast<const int4*>(hi ? (m_e   + erow) : (m_c   + crow));
        const int4* s2 = reinterpret_cast<const int4*>(hi ? (t_e   + erow) : (t_c   + crow));
        float4* d0 = reinterpret_cast<float4*>(out + 640 + (size_t)(0 + hi) * OUT_TENSOR_SZ + (size_t)r * L_);
        float4* d1 = reinterpret_cast<float4*>(out + 640 + (size_t)(2 + hi) * OUT_TENSOR_SZ + (size_t)r * L_);
        float4* d2 = reinterpret_cast<float4*>(out + 640 + (size_t)(4 + hi) * OUT_TENSOR_SZ + (size_t)r * L_);
        int4 w0 = s0[q];
        int4 w1 = s1[q];
        int4 w2 = s2[q];
        d0[q] = make_float4((float)w0.x, (float)w0.y, (float)w0.z, (float)w0.w);
        d1[q] = make_float4((float)w1.x, (float)w1.y, (float)w1.z, (float)w1.w);
        d2[q] = make_float4((float)w2.x, (float)w2.y, (float)w2.z, (float)w2.w);
    }
}

extern "C" void kernel_launch(void* const* d_in, const int* in_sizes, int n_in,
                              void* d_out, int out_size, void* d_ws, size_t ws_size,
                              hipStream_t stream) {
    const float* claim_vec    = (const float*)d_in[0];
    const float* evidence_vec = (const float*)d_in[1];
    const int*   ids_claim    = (const int*)d_in[2];
    const int*   ids_evidence = (const int*)d_in[3];
    const int*   masks_claim  = (const int*)d_in[4];
    const int*   masks_evid   = (const int*)d_in[5];
    const int*   token_claim  = (const int*)d_in[6];
    const int*   token_evid   = (const int*)d_in[7];

    float* out = (float*)d_out;

    fused_retriever_kernel<<<B_, 1024, 0, stream>>>(claim_vec, evidence_vec,
                                                    ids_claim, ids_evidence,
                                                    masks_claim, masks_evid,
                                                    token_claim, token_evid,
                                                    out);
}

// Round 10
// 23.706 us; speedup vs baseline: 5.3342x; 1.0110x over previous
//
#include <hip/hip_runtime.h>
#include <hip/hip_bf16.h>
#include <math.h>

// Problem constants (fixed by setup_inputs): B=128, E=512, L=128, D=128, K=5
#define B_ 128
#define E_ 512
#define L_ 128
#define D_ 128
#define K_ 5
#define N_ (B_ * E_)                 // 65536 rows
#define ROWOUT (B_ * K_)             // 640 output rows
#define OUT_TENSOR_SZ (ROWOUT * L_)  // 81920

// ---------------- Kernel 1: per-row cosine similarity (EXACT R1 math) -------
// 32 lanes per row (float4 each), 2 rows per wave, 8 rows per 256-thr block.
// Blocks 0..127 additionally write the claim-side gather for batch b=blockIdx
// (independent of top-k; ids<2^24 so float conversion is exact).
__global__ __launch_bounds__(256) void cos_kernel(const float* __restrict__ a,
                                                  const float* __restrict__ b,
                                                  const int* __restrict__ ids_c,
                                                  const int* __restrict__ m_c,
                                                  const int* __restrict__ t_c,
                                                  float* __restrict__ cosout,
                                                  float* __restrict__ out) {
    const int row  = blockIdx.x * 8 + (threadIdx.x >> 5);
    const int l32  = threadIdx.x & 31;
    const float4* a4 = reinterpret_cast<const float4*>(a) + (size_t)row * (D_ / 4) + l32;
    const float4* b4 = reinterpret_cast<const float4*>(b) + (size_t)row * (D_ / 4) + l32;
    float4 av = *a4;
    float4 bv = *b4;
    float dot = av.x * bv.x + av.y * bv.y + av.z * bv.z + av.w * bv.w;
    float na  = av.x * av.x + av.y * av.y + av.z * av.z + av.w * av.w;
    float nb  = bv.x * bv.x + bv.y * bv.y + bv.z * bv.z + bv.w * bv.w;
    #pragma unroll
    for (int o = 16; o; o >>= 1) {           // stays within each 32-lane half
        dot += __shfl_xor(dot, o);
        na  += __shfl_xor(na,  o);
        nb  += __shfl_xor(nb,  o);
    }
    if (l32 == 0) {
        const float eps = 1e-8f;
        float denom = fmaxf(sqrtf(na), eps) * fmaxf(sqrtf(nb), eps);
        cosout[row] = dot / denom;
    }

    // ---- claim-side gather: blocks 0..127, batch = blockIdx.x ----
    if (blockIdx.x < B_) {
        const int bb = blockIdx.x;
        for (int u = threadIdx.x; u < 480; u += 256) {  // 3 tensors x 5 rows x 32 int4
            const int q      = u & 31;
            const int rt     = u >> 5;                  // 0..14
            const int tensor = rt / 5;                  // 0=ids,1=masks,2=token
            const int k      = rt - tensor * 5;
            const int* src = tensor == 0 ? ids_c : (tensor == 1 ? m_c : t_c);
            const int4* sp = reinterpret_cast<const int4*>(src + (size_t)(bb * E_ + k) * L_);
            float4* dp = reinterpret_cast<float4*>(out + 640
                           + (size_t)(2 * tensor) * OUT_TENSOR_SZ
                           + (size_t)(bb * K_ + k) * L_);
            int4 w = sp[q];
            dp[q] = make_float4((float)w.x, (float)w.y, (float)w.z, (float)w.w);
        }
    }
}

// ------- Kernel 2: softmax over E + top-5 + evidence-side gather (R1 math) ----
__global__ __launch_bounds__(512) void softmax_topk_gather_kernel(
        const float* __restrict__ cosv,
        const int* __restrict__ ids_e,
        const int* __restrict__ m_e,
        const int* __restrict__ t_e,
        float* __restrict__ out) {
    const int b    = blockIdx.x;
    const int e    = threadIdx.x;          // 0..511
    const int wid  = e >> 6;
    const int lane = e & 63;

    __shared__ float red[8];
    __shared__ float ps[E_];
    __shared__ int   topidx[K_];

    float v = cosv[b * E_ + e];

    // block max
    float m = v;
    #pragma unroll
    for (int o = 32; o; o >>= 1) m = fmaxf(m, __shfl_xor(m, o));
    if (lane == 0) red[wid] = m;
    __syncthreads();
    float mall = red[0];
    #pragma unroll
    for (int i = 1; i < 8; i++) mall = fmaxf(mall, red[i]);
    __syncthreads();

    // block sum of exp
    float ex = expf(v - mall);
    float s = ex;
    #pragma unroll
    for (int o = 32; o; o >>= 1) s += __shfl_xor(s, o);
    if (lane == 0) red[wid] = s;
    __syncthreads();
    float sall = 0.f;
    #pragma unroll
    for (int i = 0; i < 8; i++) sall += red[i];

    ps[e] = ex / sall;
    __syncthreads();

    // ---- top-5 entirely within wave 0, registers only (identical to R1) ----
    if (wid == 0) {
        float vals[8];
        #pragma unroll
        for (int j = 0; j < 8; j++) vals[j] = ps[j * 64 + lane];

        for (int k = 0; k < K_; k++) {
            float val = vals[0];
            int   idx = lane;
            #pragma unroll
            for (int j = 1; j < 8; j++) {
                if (vals[j] > val) { val = vals[j]; idx = j * 64 + lane; }
            }
            // wave argmax: larger value wins; equal value -> smaller index
            #pragma unroll
            for (int o = 32; o; o >>= 1) {
                float ov = __shfl_xor(val, o);
                int   oi = __shfl_xor(idx, o);
                if (ov > val || (ov == val && oi < idx)) { val = ov; idx = oi; }
            }
            if (lane == 0) {
                out[b * K_ + k] = val;
                topidx[k] = idx;
            }
            // invalidate winner (compile-time reg index to avoid scratch)
            #pragma unroll
            for (int j = 0; j < 8; j++) {
                if ((idx >> 6) == j && (idx & 63) == lane) vals[j] = -INFINITY;
            }
        }
    }
    __syncthreads();

    // ---- evidence-side gather: wave k handles output row r = b*K + k ----
    if (wid < K_) {
        const int k = wid;
        const int r = b * K_ + k;
        const size_t erow = (size_t)(b * E_ + topidx[k]) * L_;
        for (int u = lane; u < 96; u += 64) {       // 3 tensors x 32 int4
            const int q      = u & 31;
            const int tensor = u >> 5;              // 0=ids,1=masks,2=token
            const int* src = tensor == 0 ? ids_e : (tensor == 1 ? m_e : t_e);
            const int4* sp = reinterpret_cast<const int4*>(src + erow);
            float4* dp = reinterpret_cast<float4*>(out + 640
                           + (size_t)(2 * tensor + 1) * OUT_TENSOR_SZ
                           + (size_t)r * L_);
            int4 w = sp[q];
            dp[q] = make_float4((float)w.x, (float)w.y, (float)w.z, (float)w.w);
        }
    }
}

extern "C" void kernel_launch(void* const* d_in, const int* in_sizes, int n_in,
                              void* d_out, int out_size, void* d_ws, size_t ws_size,
                              hipStream_t stream) {
    const float* claim_vec    = (const float*)d_in[0];
    const float* evidence_vec = (const float*)d_in[1];
    const int*   ids_claim    = (const int*)d_in[2];
    const int*   ids_evidence = (const int*)d_in[3];
    const int*   masks_claim  = (const int*)d_in[4];
    const int*   masks_evid   = (const int*)d_in[5];
    const int*   token_claim  = (const int*)d_in[6];
    const int*   token_evid   = (const int*)d_in[7];

    float* cos_ws = (float*)d_ws;   // N_ floats
    float* out    = (float*)d_out;

    // 1) cosine (8 rows per 256-thread block) + claim-side gather
    cos_kernel<<<N_ / 8, 256, 0, stream>>>(claim_vec, evidence_vec,
                                           ids_claim, masks_claim, token_claim,
                                           cos_ws, out);
    // 2) softmax + top-5 + evidence-side gather
    softmax_topk_gather_kernel<<<B_, 512, 0, stream>>>(cos_ws,
                                                       ids_evidence, masks_evid,
                                                       token_evid, out);
}